// Round 3
// baseline (625.475 us; speedup 1.0000x reference)
//
#include <hip/hip_runtime.h>

// CoRACommonEmbedding: out[t] = emb[x[t]] + (lora_B[x[t]] . effA) * SCALING
//   effA[r][d] = lora_A[r][d] * (rank_pattern[r] > 0.1)
//
// Layout: 32 lanes per token, each lane owns one float4 of the D=128 row.
// Each thread keeps its 8x{float4} column slice of effA in registers.
//
// v2 changes vs baseline (617 us):
//  - 4-way interleaved unroll of the token loop: 4 independent
//    idx->gather->fma->store chains in flight per thread (latency-bound fix;
//    baseline had ONE random-gather chain per 32-lane group, ~2 serialized
//    cache-miss latencies per trip x 25 trips).
//  - non-temporal stores for the 419 MB output stream so it does not evict
//    the 244 MiB emb table from the 256 MiB L3 (keeps gathers L3-resident).
//    (uses clang native ext_vector_type for the builtin — HIP float4 is a
//    class and __builtin_nontemporal_store rejects it.)

constexpr int D = 128;
constexpr int R = 8;
constexpr float SCALING = 2.0f;        // LORA_ALPHA / R = 16 / 8
constexpr float RANK_THRESHOLD = 0.1f;

typedef float f32x4 __attribute__((ext_vector_type(4)));

__device__ __forceinline__ void nt_store4(float* p, const float4& v) {
    f32x4 t;
    t.x = v.x; t.y = v.y; t.z = v.z; t.w = v.w;
    __builtin_nontemporal_store(t, reinterpret_cast<f32x4*>(p));
}

__global__ __launch_bounds__(256) void cora_embed_kernel(
    const int*   __restrict__ x,            // [N] token ids
    const float* __restrict__ emb,          // [VOCAB, D]
    const float* __restrict__ lora_A,       // [R, D]
    const float* __restrict__ lora_B,       // [VOCAB, R]
    const float* __restrict__ rank_pattern, // [R]
    float*       __restrict__ out,          // [N, D]
    int n_tokens)
{
    const int d4  = threadIdx.x & 31;   // which float4 of the 128-wide row
    const int row = threadIdx.x >> 5;   // token slot within block: 0..7

    // Per-thread column slice of effective_A (masked + pre-scaled).
    float4 A4[R];
#pragma unroll
    for (int r = 0; r < R; ++r) {
        const float g = (rank_pattern[r] > RANK_THRESHOLD) ? SCALING : 0.0f;
        float4 a = reinterpret_cast<const float4*>(lora_A)[r * (D / 4) + d4];
        A4[r].x = a.x * g;
        A4[r].y = a.y * g;
        A4[r].z = a.z * g;
        A4[r].w = a.w * g;
    }

    const int stride = gridDim.x * 8;   // token slots per pass
    int t = blockIdx.x * 8 + row;

    // ---- main loop: 4 tokens per trip, fully independent chains ----
    for (; t + 3 * stride < n_tokens; t += 4 * stride) {
        const int t0 = t;
        const int t1 = t + stride;
        const int t2 = t + 2 * stride;
        const int t3 = t + 3 * stride;

        // 4 independent index loads (L1-broadcast across the 32-lane group)
        const int i0 = x[t0];
        const int i1 = x[t1];
        const int i2 = x[t2];
        const int i3 = x[t3];

        const float4* e0 = reinterpret_cast<const float4*>(emb + (size_t)i0 * D);
        const float4* e1 = reinterpret_cast<const float4*>(emb + (size_t)i1 * D);
        const float4* e2 = reinterpret_cast<const float4*>(emb + (size_t)i2 * D);
        const float4* e3 = reinterpret_cast<const float4*>(emb + (size_t)i3 * D);
        const float4* B0 = reinterpret_cast<const float4*>(lora_B + (size_t)i0 * R);
        const float4* B1 = reinterpret_cast<const float4*>(lora_B + (size_t)i1 * R);
        const float4* B2 = reinterpret_cast<const float4*>(lora_B + (size_t)i2 * R);
        const float4* B3 = reinterpret_cast<const float4*>(lora_B + (size_t)i3 * R);

        // 12 independent gather loads in flight
        float4 o0 = e0[d4];
        float4 o1 = e1[d4];
        float4 o2 = e2[d4];
        float4 o3 = e3[d4];
        float4 b00 = B0[0], b01 = B0[1];
        float4 b10 = B1[0], b11 = B1[1];
        float4 b20 = B2[0], b21 = B2[1];
        float4 b30 = B3[0], b31 = B3[1];

        const float b0[R] = {b00.x, b00.y, b00.z, b00.w, b01.x, b01.y, b01.z, b01.w};
        const float b1[R] = {b10.x, b10.y, b10.z, b10.w, b11.x, b11.y, b11.z, b11.w};
        const float b2[R] = {b20.x, b20.y, b20.z, b20.w, b21.x, b21.y, b21.z, b21.w};
        const float b3[R] = {b30.x, b30.y, b30.z, b30.w, b31.x, b31.y, b31.z, b31.w};

#pragma unroll
        for (int r = 0; r < R; ++r) {
            o0.x = fmaf(b0[r], A4[r].x, o0.x);
            o0.y = fmaf(b0[r], A4[r].y, o0.y);
            o0.z = fmaf(b0[r], A4[r].z, o0.z);
            o0.w = fmaf(b0[r], A4[r].w, o0.w);
            o1.x = fmaf(b1[r], A4[r].x, o1.x);
            o1.y = fmaf(b1[r], A4[r].y, o1.y);
            o1.z = fmaf(b1[r], A4[r].z, o1.z);
            o1.w = fmaf(b1[r], A4[r].w, o1.w);
            o2.x = fmaf(b2[r], A4[r].x, o2.x);
            o2.y = fmaf(b2[r], A4[r].y, o2.y);
            o2.z = fmaf(b2[r], A4[r].z, o2.z);
            o2.w = fmaf(b2[r], A4[r].w, o2.w);
            o3.x = fmaf(b3[r], A4[r].x, o3.x);
            o3.y = fmaf(b3[r], A4[r].y, o3.y);
            o3.z = fmaf(b3[r], A4[r].z, o3.z);
            o3.w = fmaf(b3[r], A4[r].w, o3.w);
        }

        // streaming (non-temporal) stores: don't evict the emb table from L3
        nt_store4(out + (size_t)t0 * D + d4 * 4, o0);
        nt_store4(out + (size_t)t1 * D + d4 * 4, o1);
        nt_store4(out + (size_t)t2 * D + d4 * 4, o2);
        nt_store4(out + (size_t)t3 * D + d4 * 4, o3);
    }

    // ---- tail: remaining trips (25 = 4*6 + 1 per thread at grid=4096) ----
    for (; t < n_tokens; t += stride) {
        const int idx = x[t];
        const float4* erow = reinterpret_cast<const float4*>(emb + (size_t)idx * D);
        const float4* brow = reinterpret_cast<const float4*>(lora_B + (size_t)idx * R);

        float4 o  = erow[d4];
        float4 b0 = brow[0];
        float4 b1 = brow[1];
        const float b[R] = {b0.x, b0.y, b0.z, b0.w, b1.x, b1.y, b1.z, b1.w};

#pragma unroll
        for (int r = 0; r < R; ++r) {
            o.x = fmaf(b[r], A4[r].x, o.x);
            o.y = fmaf(b[r], A4[r].y, o.y);
            o.z = fmaf(b[r], A4[r].z, o.z);
            o.w = fmaf(b[r], A4[r].w, o.w);
        }

        nt_store4(out + (size_t)t * D + d4 * 4, o);
    }
}

extern "C" void kernel_launch(void* const* d_in, const int* in_sizes, int n_in,
                              void* d_out, int out_size, void* d_ws, size_t ws_size,
                              hipStream_t stream) {
    const int*   x            = (const int*)d_in[0];
    const float* emb          = (const float*)d_in[1];
    const float* lora_A       = (const float*)d_in[2];
    const float* lora_B       = (const float*)d_in[3];
    const float* rank_pattern = (const float*)d_in[4];
    float*       out          = (float*)d_out;

    const int n_tokens = in_sizes[0];   // B * L = 819200

    // 4096 blocks x 256 threads: 8 token-slots/block -> 25 trips/thread
    // (6 unrolled-by-4 + 1 tail); saturates all 256 CUs.
    const int grid = 4096;
    hipLaunchKernelGGL(cora_embed_kernel, dim3(grid), dim3(256), 0, stream,
                       x, emb, lora_A, lora_B, rank_pattern, out, n_tokens);
}